// Round 1
// baseline (4994.256 us; speedup 1.0000x reference)
//
#include <hip/hip_runtime.h>
#include <stdint.h>

// Problem constants
#define S_LEN 2048
#define DIM   2048
#define NH    16
#define NKV   4
#define HD    128
#define QKV_E 3072   // (16 + 2*4) * 128

typedef unsigned short u16;
typedef __attribute__((ext_vector_type(8))) short short8;   // 8 x bf16 MFMA operand
typedef __attribute__((ext_vector_type(4))) float floatx4;  // MFMA accumulator

__device__ __forceinline__ u16 f2bf(float f) {
  unsigned u = __float_as_uint(f);
  u = u + 0x7fffu + ((u >> 16) & 1u);   // RNE
  return (u16)(u >> 16);
}
__device__ __forceinline__ float bf2f(u16 b) {
  return __uint_as_float(((unsigned)b) << 16);
}

// ---------------- f32 -> bf16 cast (vectorized) ----------------
__global__ __launch_bounds__(256) void cast_bf16_k(const float* __restrict__ in,
                                                   u16* __restrict__ out, int n4) {
  int i = blockIdx.x * blockDim.x + threadIdx.x;
  int stride = gridDim.x * blockDim.x;
  for (; i < n4; i += stride) {
    float4 v = ((const float4*)in)[i];
    ushort4 o;
    o.x = f2bf(v.x); o.y = f2bf(v.y); o.z = f2bf(v.z); o.w = f2bf(v.w);
    ((ushort4*)out)[i] = o;
  }
}

// ---------------- bf16 GEMM, C = A * B^T (both K-major) ----------------
// A: [M][K] bf16, B: [N][K] bf16, C: [M][N] f32.  128x128 tile, BK=32,
// 4 waves (2x2 of 64x64), 16x16x32 MFMA. m97-style global_load_lds staging.
#define GT 128
#define GBK 32

__device__ __forceinline__ void gload16(const void* g, void* l) {
  __builtin_amdgcn_global_load_lds((const __attribute__((address_space(1))) void*)g,
                                   (__attribute__((address_space(3))) void*)l, 16, 0, 0);
}

__global__ __launch_bounds__(256) void gemm_bt(const u16* __restrict__ A,
                                               const u16* __restrict__ B,
                                               float* __restrict__ C,
                                               int M, int N, int K) {
  __shared__ u16 As[GT * GBK];
  __shared__ u16 Bs[GT * GBK];
  const int tid  = threadIdx.x;
  const int wid  = tid >> 6;
  const int lane = tid & 63;
  const int m0 = blockIdx.y * GT;
  const int n0 = blockIdx.x * GT;
  const int wr = wid >> 1, wc = wid & 1;   // wave -> 64x64 quadrant

  floatx4 acc[4][4] = {};

  const int srow   = lane >> 2;          // 0..15 row within 16-row group
  const int schunk = (lane & 3) * 8;     // 8-elem (16B) chunk within row
  const int fr = lane & 15;              // fragment row (A row / B^T row)
  const int kc = (lane >> 4) * 8;        // fragment k-chunk

  for (int k0 = 0; k0 < K; k0 += GBK) {
#pragma unroll
    for (int i = 0; i < 2; ++i) {
      int r = i * 64 + wid * 16 + srow;
      // LDS dest base is wave-uniform; HW adds lane*16B (linear [128][32] tile)
      gload16(A + (size_t)(m0 + r) * K + k0 + schunk, As + (i * 64 + wid * 16) * GBK);
      gload16(B + (size_t)(n0 + r) * K + k0 + schunk, Bs + (i * 64 + wid * 16) * GBK);
    }
    __syncthreads();   // drains vmcnt for global_load_lds

    short8 af[4], bf[4];
#pragma unroll
    for (int m = 0; m < 4; ++m)
      af[m] = *(const short8*)(As + (wr * 64 + m * 16 + fr) * GBK + kc);
#pragma unroll
    for (int n = 0; n < 4; ++n)
      bf[n] = *(const short8*)(Bs + (wc * 64 + n * 16 + fr) * GBK + kc);
#pragma unroll
    for (int m = 0; m < 4; ++m)
#pragma unroll
      for (int n = 0; n < 4; ++n)
        acc[m][n] = __builtin_amdgcn_mfma_f32_16x16x32_bf16(af[m], bf[n], acc[m][n], 0, 0, 0);
    __syncthreads();
  }

  // C/D layout: row = (lane>>4)*4 + r, col = lane&15  (m89/m91-verified)
#pragma unroll
  for (int m = 0; m < 4; ++m)
#pragma unroll
    for (int n = 0; n < 4; ++n) {
      int row = m0 + wr * 64 + m * 16 + (lane >> 4) * 4;
      int col = n0 + wc * 64 + n * 16 + (lane & 15);
      float* cp = C + (size_t)row * N + col;
#pragma unroll
      for (int r = 0; r < 4; ++r) cp[(size_t)r * N] = acc[m][n][r];
    }
}

// ---------------- RMSNorm + RoPE + split/cast ----------------
// qkv f32 [B*S][3072] -> Qb [B][16][S][128], Kb [B][4][S][128], Vb [B][4][S][128] (bf16)
__global__ __launch_bounds__(256) void normrope(const float* __restrict__ qkv,
                                                const float* __restrict__ freqs,
                                                const float* __restrict__ qw,
                                                const float* __restrict__ kw,
                                                u16* __restrict__ Qb,
                                                u16* __restrict__ Kb,
                                                u16* __restrict__ Vb) {
  int row  = blockIdx.x * 4 + (threadIdx.x >> 6);   // over B*S*24
  int lane = threadIdx.x & 63;
  int bs = row / 24, h = row % 24;
  int b = bs >> 11, s = bs & (S_LEN - 1);
  const float* src = qkv + (size_t)bs * QKV_E + h * HD;
  float2 x = *(const float2*)(src + 2 * lane);

  float ss = x.x * x.x + x.y * x.y;
#pragma unroll
  for (int off = 32; off; off >>= 1) ss += __shfl_xor(ss, off);
  float rn = rsqrtf(ss * (1.0f / 128.0f) + 1e-5f);

  ushort2 o;
  if (h < 20) {
    const float* w = (h < 16) ? qw : kw;
    float x0 = x.x * rn * w[2 * lane];
    float x1 = x.y * rn * w[2 * lane + 1];
    float2 f = *(const float2*)(freqs + (size_t)s * 128 + 2 * lane);  // cos, sin
    o.x = f2bf(x0 * f.x - x1 * f.y);
    o.y = f2bf(x1 * f.x + x0 * f.y);
  } else {
    o.x = f2bf(x.x);
    o.y = f2bf(x.y);
  }
  u16* dst;
  if (h < 16)      dst = Qb + ((size_t)(b * NH  + h)      * S_LEN + s) * HD;
  else if (h < 20) dst = Kb + ((size_t)(b * NKV + h - 16) * S_LEN + s) * HD;
  else             dst = Vb + ((size_t)(b * NKV + h - 20) * S_LEN + s) * HD;
  *(ushort2*)(dst + 2 * lane) = o;
}

// ---------------- causal GQA attention, one wave per query row ----------------
// Online softmax in f32; K/V bf16. Yb out: [B][S][16][128] bf16.
__global__ __launch_bounds__(256) void attn_vec(const u16* __restrict__ Qb,
                                                const u16* __restrict__ Kb,
                                                const u16* __restrict__ Vb,
                                                u16* __restrict__ Yb) {
  int idx  = blockIdx.x * 4 + (threadIdx.x >> 6);   // over B*NH*S
  int lane = threadIdx.x & 63;
  int b = idx >> 15;             // NH*S = 32768
  int h = (idx >> 11) & 15;
  int s = idx & (S_LEN - 1);

  const u16* qp = Qb + ((size_t)(b * NH + h) * S_LEN + s) * HD + 2 * lane;
  float q0 = bf2f(qp[0]), q1 = bf2f(qp[1]);
  const u16* kp = Kb + (size_t)(b * NKV + (h >> 2)) * S_LEN * HD + 2 * lane;
  const u16* vp = Vb + (size_t)(b * NKV + (h >> 2)) * S_LEN * HD + 2 * lane;

  float m = -INFINITY, lsum = 0.f, a0 = 0.f, a1 = 0.f;
  const float scale = 0.08838834764831845f;  // 1/sqrt(128)

  for (int j = 0; j <= s; ++j) {
    ushort2 kv = *(const ushort2*)(kp + (size_t)j * HD);
    float part = q0 * bf2f(kv.x) + q1 * bf2f(kv.y);
#pragma unroll
    for (int off = 32; off; off >>= 1) part += __shfl_xor(part, off);
    float sc = part * scale;
    float mn = fmaxf(m, sc);
    float corr = __expf(m - mn);   // first iter: exp(-inf)=0
    float p    = __expf(sc - mn);
    lsum = lsum * corr + p;
    ushort2 vv = *(const ushort2*)(vp + (size_t)j * HD);
    a0 = a0 * corr + p * bf2f(vv.x);
    a1 = a1 * corr + p * bf2f(vv.y);
    m = mn;
  }
  float inv = 1.0f / lsum;
  ushort2 o;
  o.x = f2bf(a0 * inv);
  o.y = f2bf(a1 * inv);
  *(ushort2*)(Yb + ((size_t)(b * S_LEN + s) * DIM) + h * HD + 2 * lane) = o;
}

// ---------------- launch ----------------
extern "C" void kernel_launch(void* const* d_in, const int* in_sizes, int n_in,
                              void* d_out, int out_size, void* d_ws, size_t ws_size,
                              hipStream_t stream) {
  const float* x     = (const float*)d_in[0];
  const float* freqs = (const float*)d_in[1];
  // d_in[2] = mask (causal tril) — not needed, causality computed directly
  const float* wqkv  = (const float*)d_in[3];
  const float* wo    = (const float*)d_in[4];
  const float* qw    = (const float*)d_in[5];
  const float* kw    = (const float*)d_in[6];
  float* out = (float*)d_out;
  char* ws = (char*)d_ws;

  const int M = 2 * S_LEN;  // 4096 rows (B*S)

  // workspace layout (bytes)
  u16*   xb    = (u16*)(ws);                         // 4096x2048 bf16   = 16 MB
  u16*   wqkvb = (u16*)(ws + 16777216);              // 3072x2048 bf16   = 12 MB
  u16*   wob   = (u16*)(ws + 29360128);              // 2048x2048 bf16   = 8 MB
  float* qkvf  = (float*)(ws + 37748736);            // 4096x3072 f32    = 48 MB
  u16*   Qb    = (u16*)(ws + 88080384);              // 2x16x2048x128    = 16 MB
  u16*   Kb    = (u16*)(ws + 104857600);             // 2x4x2048x128     = 4 MB
  u16*   Vb    = (u16*)(ws + 109051904);             // 2x4x2048x128     = 4 MB
  u16*   Yb    = (u16*)(ws + 113246208);             // 4096x2048 bf16   = 16 MB
  // total ~124 MB

  cast_bf16_k<<<2048, 256, 0, stream>>>(x,    xb,    M * DIM / 4);
  cast_bf16_k<<<2048, 256, 0, stream>>>(wqkv, wqkvb, QKV_E * DIM / 4);
  cast_bf16_k<<<2048, 256, 0, stream>>>(wo,   wob,   DIM * DIM / 4);

  gemm_bt<<<dim3(QKV_E / GT, M / GT), 256, 0, stream>>>(xb, wqkvb, qkvf, M, QKV_E, DIM);

  normrope<<<(M * 24) / 4, 256, 0, stream>>>(qkvf, freqs, qw, kw, Qb, Kb, Vb);

  attn_vec<<<(2 * NH * S_LEN) / 4, 256, 0, stream>>>(Qb, Kb, Vb, Yb);

  gemm_bt<<<dim3(DIM / GT, M / GT), 256, 0, stream>>>(Yb, wob, out, M, DIM, DIM);
}

// Round 2
// 515.726 us; speedup vs baseline: 9.6839x; 9.6839x over previous
//
#include <hip/hip_runtime.h>
#include <stdint.h>

// Problem constants
#define S_LEN 2048
#define DIM   2048
#define NH    16
#define NKV   4
#define HD    128
#define QKV_E 3072   // (16 + 2*4) * 128

typedef unsigned short u16;
typedef __attribute__((ext_vector_type(8))) short short8;   // 8 x bf16 MFMA operand
typedef __attribute__((ext_vector_type(4))) float floatx4;  // MFMA accumulator

__device__ __forceinline__ u16 f2bf(float f) {
  unsigned u = __float_as_uint(f);
  u = u + 0x7fffu + ((u >> 16) & 1u);   // RNE
  return (u16)(u >> 16);
}
__device__ __forceinline__ float bf2f(u16 b) {
  return __uint_as_float(((unsigned)b) << 16);
}

// ---------------- f32 -> bf16 cast (vectorized) ----------------
__global__ __launch_bounds__(256) void cast_bf16_k(const float* __restrict__ in,
                                                   u16* __restrict__ out, int n4) {
  int i = blockIdx.x * blockDim.x + threadIdx.x;
  int stride = gridDim.x * blockDim.x;
  for (; i < n4; i += stride) {
    float4 v = ((const float4*)in)[i];
    ushort4 o;
    o.x = f2bf(v.x); o.y = f2bf(v.y); o.z = f2bf(v.z); o.w = f2bf(v.w);
    ((ushort4*)out)[i] = o;
  }
}

// ---------------- bf16 GEMM, C = A * B^T (both K-major) ----------------
#define GT 128
#define GBK 32

__device__ __forceinline__ void gload16(const void* g, void* l) {
  __builtin_amdgcn_global_load_lds((const __attribute__((address_space(1))) void*)g,
                                   (__attribute__((address_space(3))) void*)l, 16, 0, 0);
}

__global__ __launch_bounds__(256) void gemm_bt(const u16* __restrict__ A,
                                               const u16* __restrict__ B,
                                               float* __restrict__ C,
                                               int M, int N, int K) {
  __shared__ u16 As[GT * GBK];
  __shared__ u16 Bs[GT * GBK];
  const int tid  = threadIdx.x;
  const int wid  = tid >> 6;
  const int lane = tid & 63;
  const int m0 = blockIdx.y * GT;
  const int n0 = blockIdx.x * GT;
  const int wr = wid >> 1, wc = wid & 1;

  floatx4 acc[4][4] = {};

  const int srow   = lane >> 2;
  const int schunk = (lane & 3) * 8;
  const int fr = lane & 15;
  const int kc = (lane >> 4) * 8;

  for (int k0 = 0; k0 < K; k0 += GBK) {
#pragma unroll
    for (int i = 0; i < 2; ++i) {
      int r = i * 64 + wid * 16 + srow;
      gload16(A + (size_t)(m0 + r) * K + k0 + schunk, As + (i * 64 + wid * 16) * GBK);
      gload16(B + (size_t)(n0 + r) * K + k0 + schunk, Bs + (i * 64 + wid * 16) * GBK);
    }
    __syncthreads();

    short8 af[4], bf[4];
#pragma unroll
    for (int m = 0; m < 4; ++m)
      af[m] = *(const short8*)(As + (wr * 64 + m * 16 + fr) * GBK + kc);
#pragma unroll
    for (int n = 0; n < 4; ++n)
      bf[n] = *(const short8*)(Bs + (wc * 64 + n * 16 + fr) * GBK + kc);
#pragma unroll
    for (int m = 0; m < 4; ++m)
#pragma unroll
      for (int n = 0; n < 4; ++n)
        acc[m][n] = __builtin_amdgcn_mfma_f32_16x16x32_bf16(af[m], bf[n], acc[m][n], 0, 0, 0);
    __syncthreads();
  }

#pragma unroll
  for (int m = 0; m < 4; ++m)
#pragma unroll
    for (int n = 0; n < 4; ++n) {
      int row = m0 + wr * 64 + m * 16 + (lane >> 4) * 4;
      int col = n0 + wc * 64 + n * 16 + (lane & 15);
      float* cp = C + (size_t)row * N + col;
#pragma unroll
      for (int r = 0; r < 4; ++r) cp[(size_t)r * N] = acc[m][n][r];
    }
}

// ---------------- RMSNorm + RoPE + split/cast ----------------
// qkv f32 [B*S][3072] -> Qb [B][16][S][128], Kb [B][4][S][128] (bf16),
//                        Vt [B][4][128][S] (bf16, transposed for PV B-fragments)
__global__ __launch_bounds__(256) void normrope(const float* __restrict__ qkv,
                                                const float* __restrict__ freqs,
                                                const float* __restrict__ qw,
                                                const float* __restrict__ kw,
                                                u16* __restrict__ Qb,
                                                u16* __restrict__ Kb,
                                                u16* __restrict__ Vt) {
  int row  = blockIdx.x * 4 + (threadIdx.x >> 6);   // over B*S*24
  int lane = threadIdx.x & 63;
  int bs = row / 24, h = row % 24;
  int b = bs >> 11, s = bs & (S_LEN - 1);
  const float* src = qkv + (size_t)bs * QKV_E + h * HD;
  float2 x = *(const float2*)(src + 2 * lane);

  float ss = x.x * x.x + x.y * x.y;
#pragma unroll
  for (int off = 32; off; off >>= 1) ss += __shfl_xor(ss, off);
  float rn = rsqrtf(ss * (1.0f / 128.0f) + 1e-5f);

  if (h < 20) {
    const float* w = (h < 16) ? qw : kw;
    float x0 = x.x * rn * w[2 * lane];
    float x1 = x.y * rn * w[2 * lane + 1];
    float2 f = *(const float2*)(freqs + (size_t)s * 128 + 2 * lane);  // cos, sin
    ushort2 o;
    o.x = f2bf(x0 * f.x - x1 * f.y);
    o.y = f2bf(x1 * f.x + x0 * f.y);
    u16* dst = (h < 16) ? (Qb + ((size_t)(b * NH  + h)      * S_LEN + s) * HD)
                        : (Kb + ((size_t)(b * NKV + h - 16) * S_LEN + s) * HD);
    *(ushort2*)(dst + 2 * lane) = o;
  } else {
    // V: no norm/rope; write transposed [hv][d][s]
    u16* dst = Vt + (size_t)(b * NKV + (h - 20)) * HD * S_LEN;
    dst[(size_t)(2 * lane)     * S_LEN + s] = f2bf(x.x);
    dst[(size_t)(2 * lane + 1) * S_LEN + s] = f2bf(x.y);
  }
}

// ---------------- MFMA flash attention (causal GQA) ----------------
// Block: (b, h, 64 q-rows), 4 waves x 16 q-rows. 32-key steps.
// Ks  [32][128] bf16, swizzled byte ^= ((row&7)<<4)  (256B rows)
// VtS [128][32] bf16, swizzled byte ^= ((row&3)<<4)  (64B rows)
// Ps  per-wave [16][40] bf16 (pad 40 to break read conflicts)
#define QT 64
#define KT 32

__global__ __launch_bounds__(256) void attn_mfma(const u16* __restrict__ Qb,
                                                 const u16* __restrict__ Kb,
                                                 const u16* __restrict__ Vt,
                                                 u16* __restrict__ Yb) {
  __shared__ u16 Ks[KT * HD];        // 8 KB
  __shared__ u16 VtS[HD * KT];       // 8 KB
  __shared__ u16 Ps[4][16 * 40];     // 5 KB

  const int wid  = threadIdx.x >> 6;
  const int lane = threadIdx.x & 63;
  const int b = blockIdx.z, h = blockIdx.y;
  const int q0 = blockIdx.x * QT;
  const int hv = h >> 2;

  const u16* Qp = Qb + ((size_t)(b * NH  + h)  * S_LEN) * HD;
  const u16* Kp = Kb + ((size_t)(b * NKV + hv) * S_LEN) * HD;
  const u16* Vp = Vt + ((size_t)(b * NKV + hv) * HD) * S_LEN;

  // Q fragments: lane holds Q[q0+wid*16+(lane&15)][ds*32+(lane>>4)*8 ..+7]
  short8 qf[4];
  {
    const u16* qrow = Qp + (size_t)(q0 + wid * 16 + (lane & 15)) * HD + (lane >> 4) * 8;
#pragma unroll
    for (int ds = 0; ds < 4; ++ds) qf[ds] = *(const short8*)(qrow + ds * 32);
  }

  floatx4 Oacc[8] = {};
  float mrow[4] = {-INFINITY, -INFINITY, -INFINITY, -INFINITY};
  float lrow[4] = {};
  const float scale = 0.08838834764831845f;

  const int kend = q0 + QT;
  for (int k0 = 0; k0 < kend; k0 += KT) {
    // ---- stage K tile: rows wid*8 .. wid*8+7 (2 gload16 per wave)
#pragma unroll
    for (int i = 0; i < 2; ++i) {
      int rbase = wid * 8 + i * 4;
      int r = rbase + (lane >> 4);          // LDS row this lane feeds
      int c = (lane & 15) * 16;             // byte col within 256B row
      const char* src = (const char*)Kp + (size_t)(k0 + r) * 256 + (c ^ ((r & 7) << 4));
      gload16(src, (char*)Ks + rbase * 256);
    }
    // ---- stage Vt tile: rows wid*32 .. +31 (2 gload16 per wave)
#pragma unroll
    for (int i = 0; i < 2; ++i) {
      int rbase = wid * 32 + i * 16;
      int r = rbase + (lane >> 2);          // d-row
      int c = (lane & 3) * 16;              // byte col within 64B row
      const char* src = (const char*)Vp + ((size_t)r * S_LEN + k0) * 2 + (c ^ ((r & 3) << 4));
      gload16(src, (char*)VtS + rbase * 64);
    }
    __syncthreads();

    // ---- QK^T: scores[kt] 16q x 16k, q=(lane>>4)*4+r, k=lane&15
    floatx4 sacc[2] = {};
#pragma unroll
    for (int kt = 0; kt < 2; ++kt) {
      int krow = kt * 16 + (lane & 15);
      const char* kbase = (const char*)Ks + krow * 256;
      int swz = (krow & 7) << 4;
#pragma unroll
      for (int ds = 0; ds < 4; ++ds) {
        int c = ds * 64 + (lane >> 4) * 16;
        short8 kf = *(const short8*)(kbase + (c ^ swz));
        sacc[kt] = __builtin_amdgcn_mfma_f32_16x16x32_bf16(qf[ds], kf, sacc[kt], 0, 0, 0);
      }
    }

    // ---- online softmax (per q row; rows live in 16-lane groups)
    const int kg0 = k0 + (lane & 15);
    const int qgb = q0 + wid * 16 + (lane >> 4) * 4;
#pragma unroll
    for (int r = 0; r < 4; ++r) {
      int qg = qgb + r;
      float s0 = (kg0      <= qg) ? sacc[0][r] * scale : -1e30f;
      float s1 = (kg0 + 16 <= qg) ? sacc[1][r] * scale : -1e30f;
      float mx = fmaxf(s0, s1);
#pragma unroll
      for (int off = 8; off; off >>= 1) mx = fmaxf(mx, __shfl_xor(mx, off));
      float mnew = fmaxf(mrow[r], mx);
      float corr = __expf(mrow[r] - mnew);
      float p0 = __expf(s0 - mnew);
      float p1 = __expf(s1 - mnew);
      float psum = p0 + p1;
#pragma unroll
      for (int off = 8; off; off >>= 1) psum += __shfl_xor(psum, off);
      lrow[r] = lrow[r] * corr + psum;
      mrow[r] = mnew;
#pragma unroll
      for (int dt = 0; dt < 8; ++dt) Oacc[dt][r] *= corr;
      int prow = (lane >> 4) * 4 + r;
      Ps[wid][prow * 40 + (lane & 15)]      = f2bf(p0);
      Ps[wid][prow * 40 + 16 + (lane & 15)] = f2bf(p1);
    }

    // ---- PV: O[q][d] += P[q][0:32] * Vt[d][0:32]
    short8 pf = *(const short8*)(&Ps[wid][(lane & 15) * 40 + (lane >> 4) * 8]);
#pragma unroll
    for (int dt = 0; dt < 8; ++dt) {
      int vrow = dt * 16 + (lane & 15);
      int c = (lane >> 4) * 16;
      short8 vf = *(const short8*)((const char*)VtS + vrow * 64 + (c ^ ((vrow & 3) << 4)));
      Oacc[dt] = __builtin_amdgcn_mfma_f32_16x16x32_bf16(pf, vf, Oacc[dt], 0, 0, 0);
    }
    __syncthreads();
  }

  // ---- epilogue: O / l, write Yb [b][s][h*128+d]
  float linv[4];
#pragma unroll
  for (int r = 0; r < 4; ++r) linv[r] = 1.0f / lrow[r];
#pragma unroll
  for (int dt = 0; dt < 8; ++dt) {
    int d = dt * 16 + (lane & 15);
#pragma unroll
    for (int r = 0; r < 4; ++r) {
      int qg = q0 + wid * 16 + (lane >> 4) * 4 + r;
      Yb[((size_t)(b * S_LEN + qg)) * DIM + h * HD + d] = f2bf(Oacc[dt][r] * linv[r]);
    }
  }
}

// ---------------- launch ----------------
extern "C" void kernel_launch(void* const* d_in, const int* in_sizes, int n_in,
                              void* d_out, int out_size, void* d_ws, size_t ws_size,
                              hipStream_t stream) {
  const float* x     = (const float*)d_in[0];
  const float* freqs = (const float*)d_in[1];
  const float* wqkv  = (const float*)d_in[3];
  const float* wo    = (const float*)d_in[4];
  const float* qw    = (const float*)d_in[5];
  const float* kw    = (const float*)d_in[6];
  float* out = (float*)d_out;
  char* ws = (char*)d_ws;

  const int M = 2 * S_LEN;  // 4096 rows (B*S)

  u16*   xb    = (u16*)(ws);                         // 16 MB
  u16*   wqkvb = (u16*)(ws + 16777216);              // 12 MB
  u16*   wob   = (u16*)(ws + 29360128);              // 8 MB
  float* qkvf  = (float*)(ws + 37748736);            // 48 MB
  u16*   Qb    = (u16*)(ws + 88080384);              // 16 MB
  u16*   Kb    = (u16*)(ws + 104857600);             // 4 MB
  u16*   Vt    = (u16*)(ws + 109051904);             // 4 MB (transposed V)
  u16*   Yb    = (u16*)(ws + 113246208);             // 16 MB

  cast_bf16_k<<<2048, 256, 0, stream>>>(x,    xb,    M * DIM / 4);
  cast_bf16_k<<<2048, 256, 0, stream>>>(wqkv, wqkvb, QKV_E * DIM / 4);
  cast_bf16_k<<<2048, 256, 0, stream>>>(wo,   wob,   DIM * DIM / 4);

  gemm_bt<<<dim3(QKV_E / GT, M / GT), 256, 0, stream>>>(xb, wqkvb, qkvf, M, QKV_E, DIM);

  normrope<<<(M * 24) / 4, 256, 0, stream>>>(qkvf, freqs, qw, kw, Qb, Kb, Vt);

  attn_mfma<<<dim3(S_LEN / QT, NH, 2), 256, 0, stream>>>(Qb, Kb, Vt, Yb);

  gemm_bt<<<dim3(DIM / GT, M / GT), 256, 0, stream>>>(Yb, wob, out, M, DIM, DIM);
}

// Round 4
// 353.484 us; speedup vs baseline: 14.1286x; 1.4590x over previous
//
#include <hip/hip_runtime.h>
#include <stdint.h>

// Problem constants
#define S_LEN 2048
#define DIM   2048
#define NH    16
#define NKV   4
#define HD    128
#define QKV_E 3072   // (16 + 2*4) * 128

typedef unsigned short u16;
typedef __attribute__((ext_vector_type(8))) short short8;   // 8 x bf16 MFMA operand
typedef __attribute__((ext_vector_type(4))) float floatx4;  // MFMA accumulator

__device__ __forceinline__ u16 f2bf(float f) {
  unsigned u = __float_as_uint(f);
  u = u + 0x7fffu + ((u >> 16) & 1u);   // RNE
  return (u16)(u >> 16);
}
__device__ __forceinline__ float bf2f(u16 b) {
  return __uint_as_float(((unsigned)b) << 16);
}

// ---------------- f32 -> bf16 cast (vectorized) ----------------
__global__ __launch_bounds__(256) void cast_bf16_k(const float* __restrict__ in,
                                                   u16* __restrict__ out, int n4) {
  int i = blockIdx.x * blockDim.x + threadIdx.x;
  int stride = gridDim.x * blockDim.x;
  for (; i < n4; i += stride) {
    float4 v = ((const float4*)in)[i];
    ushort4 o;
    o.x = f2bf(v.x); o.y = f2bf(v.y); o.z = f2bf(v.z); o.w = f2bf(v.w);
    ((ushort4*)out)[i] = o;
  }
}

// ---------------- bf16 GEMM, C = A * B^T (both K-major) ----------------
#define GT 128
#define GBK 32

__device__ __forceinline__ void gload16(const void* g, void* l) {
  __builtin_amdgcn_global_load_lds((const __attribute__((address_space(1))) void*)g,
                                   (__attribute__((address_space(3))) void*)l, 16, 0, 0);
}

// obf16 != 0 -> store bf16 to Cb, else f32 to C.
__global__ __launch_bounds__(256) void gemm_bt(const u16* __restrict__ A,
                                               const u16* __restrict__ B,
                                               float* __restrict__ C,
                                               u16* __restrict__ Cb,
                                               int M, int N, int K, int obf16) {
  __shared__ u16 As[GT * GBK];
  __shared__ u16 Bs[GT * GBK];
  const int tid  = threadIdx.x;
  const int wid  = tid >> 6;
  const int lane = tid & 63;
  const int m0 = blockIdx.y * GT;
  const int n0 = blockIdx.x * GT;
  const int wr = wid >> 1, wc = wid & 1;

  floatx4 acc[4][4] = {};

  const int srow   = lane >> 2;
  const int schunk = (lane & 3) * 8;
  const int fr = lane & 15;
  const int kc = (lane >> 4) * 8;

  for (int k0 = 0; k0 < K; k0 += GBK) {
#pragma unroll
    for (int i = 0; i < 2; ++i) {
      int r = i * 64 + wid * 16 + srow;
      gload16(A + (size_t)(m0 + r) * K + k0 + schunk, As + (i * 64 + wid * 16) * GBK);
      gload16(B + (size_t)(n0 + r) * K + k0 + schunk, Bs + (i * 64 + wid * 16) * GBK);
    }
    __syncthreads();

    short8 af[4], bf[4];
#pragma unroll
    for (int m = 0; m < 4; ++m)
      af[m] = *(const short8*)(As + (wr * 64 + m * 16 + fr) * GBK + kc);
#pragma unroll
    for (int n = 0; n < 4; ++n)
      bf[n] = *(const short8*)(Bs + (wc * 64 + n * 16 + fr) * GBK + kc);
#pragma unroll
    for (int m = 0; m < 4; ++m)
#pragma unroll
      for (int n = 0; n < 4; ++n)
        acc[m][n] = __builtin_amdgcn_mfma_f32_16x16x32_bf16(af[m], bf[n], acc[m][n], 0, 0, 0);
    __syncthreads();
  }

#pragma unroll
  for (int m = 0; m < 4; ++m)
#pragma unroll
    for (int n = 0; n < 4; ++n) {
      int row = m0 + wr * 64 + m * 16 + (lane >> 4) * 4;
      int col = n0 + wc * 64 + n * 16 + (lane & 15);
      if (obf16) {
        u16* cp = Cb + (size_t)row * N + col;
#pragma unroll
        for (int r = 0; r < 4; ++r) cp[(size_t)r * N] = f2bf(acc[m][n][r]);
      } else {
        float* cp = C + (size_t)row * N + col;
#pragma unroll
        for (int r = 0; r < 4; ++r) cp[(size_t)r * N] = acc[m][n][r];
      }
    }
}

// ---------------- RMSNorm + RoPE + split/cast ----------------
// qkv bf16 [B*S][3072] -> Qb [B][16][S][128] (pre-scaled by 1/sqrt(HD)),
//                         Kb [B][4][S][128], Vt [B][4][128][S] (transposed)
__global__ __launch_bounds__(256) void normrope(const u16* __restrict__ qkv,
                                                const float* __restrict__ freqs,
                                                const float* __restrict__ qw,
                                                const float* __restrict__ kw,
                                                u16* __restrict__ Qb,
                                                u16* __restrict__ Kb,
                                                u16* __restrict__ Vt) {
  int row  = blockIdx.x * 4 + (threadIdx.x >> 6);   // over B*S*24
  int lane = threadIdx.x & 63;
  int bs = row / 24, h = row % 24;
  int b = bs >> 11, s = bs & (S_LEN - 1);
  const u16* src = qkv + (size_t)bs * QKV_E + h * HD;
  ushort2 xr = *(const ushort2*)(src + 2 * lane);
  float x0 = bf2f(xr.x), x1 = bf2f(xr.y);

  float ss = x0 * x0 + x1 * x1;
#pragma unroll
  for (int off = 32; off; off >>= 1) ss += __shfl_xor(ss, off);
  float rn = rsqrtf(ss * (1.0f / 128.0f) + 1e-5f);

  const float scale = 0.08838834764831845f;  // 1/sqrt(128), folded into Q
  if (h < 20) {
    const float* w = (h < 16) ? qw : kw;
    float y0 = x0 * rn * w[2 * lane];
    float y1 = x1 * rn * w[2 * lane + 1];
    float2 f = *(const float2*)(freqs + (size_t)s * 128 + 2 * lane);  // cos, sin
    float r0 = y0 * f.x - y1 * f.y;
    float r1 = y1 * f.x + y0 * f.y;
    ushort2 o;
    if (h < 16) { o.x = f2bf(r0 * scale); o.y = f2bf(r1 * scale); }
    else        { o.x = f2bf(r0);         o.y = f2bf(r1); }
    u16* dst = (h < 16) ? (Qb + ((size_t)(b * NH  + h)      * S_LEN + s) * HD)
                        : (Kb + ((size_t)(b * NKV + h - 16) * S_LEN + s) * HD);
    *(ushort2*)(dst + 2 * lane) = o;
  } else {
    u16* dst = Vt + (size_t)(b * NKV + (h - 20)) * HD * S_LEN;
    dst[(size_t)(2 * lane)     * S_LEN + s] = f2bf(x0);
    dst[(size_t)(2 * lane + 1) * S_LEN + s] = f2bf(x1);
  }
}

// ---------------- MFMA flash attention (causal GQA, fixed-base softmax) ----
// RMS-normed Q,K => |score| <= sqrt(128), so exp(s) never overflows f32 and
// the softmax constant cancels in O/l: no online max tracking at all.
// Block: 4 waves x 16 q-rows = 64 q-rows; processes q-tile pair {x, 31-x}
// (uniform 33 K-steps). KT=64 keys/step.
// Ks  [64][128] bf16 swz byte^=((r&7)<<4);  VtS [128][64] bf16 swz same.
// PsT per-wave [32 kpair][16 q] u32 (pad 18): P^T packed as bf16 k-pairs.
#define KT 64

__global__ __launch_bounds__(256) void attn_mfma(const u16* __restrict__ Qb,
                                                 const u16* __restrict__ Kb,
                                                 const u16* __restrict__ Vt,
                                                 u16* __restrict__ Yb) {
  __shared__ u16 Ks[KT * HD];          // 16 KB
  __shared__ u16 VtS[HD * KT];         // 16 KB
  __shared__ unsigned PsT[4][32 * 18]; // 9 KB

  const int wid  = threadIdx.x >> 6;
  const int lane = threadIdx.x & 63;
  const int gg   = lane >> 4;          // 16-lane group
  const int c16  = lane & 15;
  const int b = blockIdx.z, h = blockIdx.y, bx = blockIdx.x;
  const int hv = h >> 2;

  const u16* Qp = Qb + ((size_t)(b * NH  + h)  * S_LEN) * HD;
  const u16* Kp = Kb + ((size_t)(b * NKV + hv) * S_LEN) * HD;
  const u16* Vp = Vt + ((size_t)(b * NKV + hv) * HD) * S_LEN;

  short8 onesf;
#pragma unroll
  for (int i = 0; i < 8; ++i) onesf[i] = (short)0x3F80;  // bf16 1.0

  for (int pass = 0; pass < 2; ++pass) {
    const int qt  = pass ? (31 - bx) : bx;
    const int q0  = qt * 64;
    const int qw0 = q0 + wid * 16;     // this wave's first q row

    short8 qf[4];
    {
      const u16* qrow = Qp + (size_t)(qw0 + c16) * HD + gg * 8;
#pragma unroll
      for (int ds = 0; ds < 4; ++ds) qf[ds] = *(const short8*)(qrow + ds * 32);
    }

    floatx4 Oacc[8] = {};
    floatx4 Lacc = {};

    for (int k0 = 0; k0 < q0 + 64; k0 += KT) {
      // ---- stage K tile [64][128] (4 gload16/wave, 4 rows each)
#pragma unroll
      for (int i = 0; i < 4; ++i) {
        int rbase = wid * 16 + i * 4;
        int r = rbase + gg;
        int cb = c16 * 16;
        gload16((const char*)Kp + (size_t)(k0 + r) * 256 + (cb ^ ((r & 7) << 4)),
                (char*)Ks + rbase * 256);
      }
      // ---- stage Vt tile [128][64] (4 gload16/wave, 8 rows each)
#pragma unroll
      for (int i = 0; i < 4; ++i) {
        int rbase = wid * 32 + i * 8;
        int r = rbase + (lane >> 3);
        int cb = (lane & 7) * 16;
        gload16((const char*)Vp + (size_t)r * (S_LEN * 2) + (size_t)k0 * 2 + (cb ^ ((r & 7) << 4)),
                (char*)VtS + rbase * 128);
      }
      __syncthreads();

      if (k0 <= qw0 + 15) {   // wave has at least one unmasked (q,k)
        // ---- QK^T swapped: st[kt] = S^T tile, row=k_local, col=q
        floatx4 st[4] = {};
#pragma unroll
        for (int kt = 0; kt < 4; ++kt) {
          int krow = kt * 16 + c16;
          const char* kbase = (const char*)Ks + krow * 256;
          int swz = (krow & 7) << 4;
#pragma unroll
          for (int ds = 0; ds < 4; ++ds) {
            short8 kf = *(const short8*)(kbase + ((ds * 64 + gg * 16) ^ swz));
            st[kt] = __builtin_amdgcn_mfma_f32_16x16x32_bf16(kf, qf[ds], st[kt], 0, 0, 0);
          }
        }

        // ---- p = exp(s) (fixed-base softmax), mask, pack to P^T u32 pairs
        const int q = qw0 + c16;
        const bool full = (k0 + 63 <= qw0);
#pragma unroll
        for (int kt = 0; kt < 4; ++kt) {
          float p[4];
#pragma unroll
          for (int r = 0; r < 4; ++r) {
            int k = k0 + kt * 16 + gg * 4 + r;
            float e = __expf(st[kt][r]);
            p[r] = (full || k <= q) ? e : 0.f;
          }
          unsigned w0, w1;
          asm("v_cvt_pk_bf16_f32 %0, %1, %2" : "=v"(w0) : "v"(p[0]), "v"(p[1]));
          asm("v_cvt_pk_bf16_f32 %0, %1, %2" : "=v"(w1) : "v"(p[2]), "v"(p[3]));
          unsigned* pp = &PsT[wid][(kt * 8 + gg * 2) * 18 + c16];
          pp[0]  = w0;
          pp[18] = w1;
        }

        // ---- PV A-fragments from PsT (column read, pad-18 -> ~2-way)
        short8 pfr[2];
#pragma unroll
        for (int ktp = 0; ktp < 2; ++ktp) {
          const unsigned* pp = &PsT[wid][(ktp * 16 + gg * 4) * 18 + c16];
          unsigned u[4];
          u[0] = pp[0]; u[1] = pp[18]; u[2] = pp[36]; u[3] = pp[54];
          pfr[ktp] = *(const short8*)u;
        }

        // ---- row-sum l via ones-fragment MFMA
#pragma unroll
        for (int ktp = 0; ktp < 2; ++ktp)
          Lacc = __builtin_amdgcn_mfma_f32_16x16x32_bf16(pfr[ktp], onesf, Lacc, 0, 0, 0);

        // ---- PV
#pragma unroll
        for (int dt = 0; dt < 8; ++dt) {
          int vrow = dt * 16 + c16;
          int swzv = (vrow & 7) << 4;
#pragma unroll
          for (int ktp = 0; ktp < 2; ++ktp) {
            short8 vf = *(const short8*)((const char*)VtS + vrow * 128 + ((ktp * 64 + gg * 16) ^ swzv));
            Oacc[dt] = __builtin_amdgcn_mfma_f32_16x16x32_bf16(pfr[ktp], vf, Oacc[dt], 0, 0, 0);
          }
        }
      }
      __syncthreads();
    }

    // ---- epilogue: O / l -> Yb [b][s][h*128+d]
    float linv[4];
#pragma unroll
    for (int r = 0; r < 4; ++r) linv[r] = 1.0f / Lacc[r];
#pragma unroll
    for (int dt = 0; dt < 8; ++dt) {
      int d = dt * 16 + c16;
#pragma unroll
      for (int r = 0; r < 4; ++r) {
        int qg = qw0 + gg * 4 + r;
        Yb[((size_t)(b * S_LEN + qg)) * DIM + h * HD + d] = f2bf(Oacc[dt][r] * linv[r]);
      }
    }
  }
}

// ---------------- launch ----------------
extern "C" void kernel_launch(void* const* d_in, const int* in_sizes, int n_in,
                              void* d_out, int out_size, void* d_ws, size_t ws_size,
                              hipStream_t stream) {
  const float* x     = (const float*)d_in[0];
  const float* freqs = (const float*)d_in[1];
  const float* wqkv  = (const float*)d_in[3];
  const float* wo    = (const float*)d_in[4];
  const float* qw    = (const float*)d_in[5];
  const float* kw    = (const float*)d_in[6];
  float* out = (float*)d_out;
  char* ws = (char*)d_ws;

  const int M = 2 * S_LEN;  // 4096 rows (B*S)

  u16* xb    = (u16*)(ws);                 // 16 MB
  u16* wqkvb = (u16*)(ws + 16777216);      // 12 MB
  u16* wob   = (u16*)(ws + 29360128);      //  8 MB
  u16* qkvb  = (u16*)(ws + 37748736);      // 24 MB (bf16 GEMM output)
  u16* Qb    = (u16*)(ws + 62914560);      // 16 MB
  u16* Kb    = (u16*)(ws + 79691776);      //  4 MB
  u16* Vt    = (u16*)(ws + 83886080);      //  4 MB
  u16* Yb    = (u16*)(ws + 88080384);      // 16 MB  (end 100 MB)

  cast_bf16_k<<<2048, 256, 0, stream>>>(x,    xb,    M * DIM / 4);
  cast_bf16_k<<<2048, 256, 0, stream>>>(wqkv, wqkvb, QKV_E * DIM / 4);
  cast_bf16_k<<<2048, 256, 0, stream>>>(wo,   wob,   DIM * DIM / 4);

  gemm_bt<<<dim3(QKV_E / GT, M / GT), 256, 0, stream>>>(xb, wqkvb, nullptr, qkvb,
                                                        M, QKV_E, DIM, 1);

  normrope<<<(M * 24) / 4, 256, 0, stream>>>(qkvb, freqs, qw, kw, Qb, Kb, Vt);

  attn_mfma<<<dim3(16, NH, 2), 256, 0, stream>>>(Qb, Kb, Vt, Yb);

  gemm_bt<<<dim3(DIM / GT, M / GT), 256, 0, stream>>>(Yb, wob, out, nullptr,
                                                      M, DIM, DIM, 0);
}